// Round 7
// baseline (851.270 us; speedup 1.0000x reference)
//
#include <hip/hip_runtime.h>
#include <cstddef>

// Problem constants
#define N_NODES 50000
#define N_EDGES 800000
#define IN_DIM  128
#define EMB     32
#define ED      8
#define NLAYERS 4
#define NB      64
#define OUTD    10
#define EPS_BN  1e-5f

#define EDGE_GRID 3125   // 800000/256 exact
#define NODE_GRID 196    // ceil(50000/256)  (scan kernels)
#define NODE4_GRID 782   // ceil(50000/64)   (4-wave node kernels)
#define AU_GRID   6250   // 50000/8 (aggr+upd1)
#define NTILE_N   3125   // 50000/16 (lin_in tiles)
#define LIN_GRID  782    // ceil(3125/4)
#define ST_TPW    4
#define ST_GRID   3125   // 3125 blocks * 4 waves * 4 tiles * 16 edges = 800000 exact
#define MSG2_TPW  4
#define MSG2_GRID 3125   // same exact tiling

#define SREP 4           // stats replication; stage stride = SREP*64

typedef short bf16x8 __attribute__((ext_vector_type(8)));
typedef float f32x4  __attribute__((ext_vector_type(4)));

// ---------------- helpers ----------------

__device__ __forceinline__ unsigned short f2bf(float x) {
  union { float f; unsigned u; } v; v.f = x;
  unsigned b = v.u + 0x7FFFu + ((v.u >> 16) & 1u);
  return (unsigned short)(b >> 16);
}
__device__ __forceinline__ float bf2f(unsigned short s) {
  union { unsigned u; float f; } v; v.u = ((unsigned)s) << 16;
  return v.f;
}

// Inline BN-coef preamble from SREP-replicated stats: cf[c]=a, cf[32+c]=be-mu*a.
__device__ __forceinline__ void coef_from_stats(const float* __restrict__ stats_stage,
                                                const float* __restrict__ g,
                                                const float* __restrict__ be,
                                                float inv_count, float* __restrict__ cf) {
  if (threadIdx.x < EMB) {
    const int c = threadIdx.x;
    float s = 0.f, ss = 0.f;
#pragma unroll
    for (int r = 0; r < SREP; ++r) {
      s  += stats_stage[r*64 + c];
      ss += stats_stage[r*64 + EMB + c];
    }
    const float mu  = s * inv_count;
    const float var = ss * inv_count - mu*mu;
    const float a = g[c] * rsqrtf(var + EPS_BN);
    cf[c] = a;
    cf[EMB + c] = fmaf(-mu, a, be[c]);
  }
  __syncthreads();
}

// Per-wave stats (8 cols each, node kernels) -> LDS -> 64 atomics; has a barrier.
__device__ __forceinline__ void wave_stats_atomic(float ts[8], float tss[8],
                                                  float* __restrict__ lds_s,
                                                  float* __restrict__ lds_q,
                                                  float* __restrict__ stats_stage) {
  const int lane = threadIdx.x & 63;
  const int wv   = threadIdx.x >> 6;
#pragma unroll
  for (int j = 0; j < 8; ++j) {
    float a = ts[j], b = tss[j];
#pragma unroll
    for (int o = 32; o > 0; o >>= 1) {
      a += __shfl_down(a, o, 64);
      b += __shfl_down(b, o, 64);
    }
    ts[j] = a; tss[j] = b;
  }
  if (lane == 0) {
#pragma unroll
    for (int j = 0; j < 8; ++j) {
      lds_s[wv*8 + j] = ts[j];
      lds_q[wv*8 + j] = tss[j];
    }
  }
  __syncthreads();
  if (threadIdx.x < 64) {
    const float v = (threadIdx.x < 32) ? lds_s[threadIdx.x] : lds_q[threadIdx.x - 32];
    atomicAdd(stats_stage + ((blockIdx.x & (SREP-1)) << 6) + threadIdx.x, v);
  }
}

// ---------------- lin_in + p/q via MFMA (one 16-node tile per wave) ----------------
// Fused tail: histogram + EDGE-ORDER rec build (all coalesced; no scatter).
// A-frag: m=lane&15 (node), k=(lane>>4)*8+j. B-frag: n=lane&15 (outcol), same k.
// C/D: col=lane&15, row=(lane>>4)*4+reg [m89].
#define HSTRIDE 40  // bf16 LDS tile row stride (16B-aligned, conflict-benign)

__global__ __launch_bounds__(256) void k_lin_in_pq(
    const float* __restrict__ x, const float* __restrict__ w, const float* __restrict__ b,
    const float* __restrict__ w1, const float* __restrict__ b1, const int* __restrict__ ei,
    const float* __restrict__ ea,
    float* __restrict__ h, unsigned short* __restrict__ p, unsigned short* __restrict__ q,
    int* __restrict__ cnt, uint4* __restrict__ rec)
{
  __shared__ __align__(16) unsigned short lds_hb[4][16*HSTRIDE];
  __shared__ __align__(16) unsigned short lds_pq[4][16*HSTRIDE];
  const int lane = threadIdx.x & 63;
  const int wv   = threadIdx.x >> 6;
  const int n0i  = lane & 15;
  const int quad = lane >> 4;

  const int tile = blockIdx.x*4 + wv;
  if (tile < NTILE_N) {
    const int r0 = tile*16;
    // issue all x loads first (8 independent float4s in flight during w loads)
    float4 xa[4], xb[4];
#pragma unroll
    for (int kb = 0; kb < 4; ++kb) {
      xa[kb] = *(const float4*)(x + (size_t)(r0 + n0i)*IN_DIM + kb*32 + quad*8);
      xb[kb] = *(const float4*)(x + (size_t)(r0 + n0i)*IN_DIM + kb*32 + quad*8 + 4);
    }
    // B frags for lin_in W (128x32 f32, row-major) — 4 k-blocks x {lo,hi}
    bf16x8 BwL[4], BwH[4];
#pragma unroll
    for (int kb = 0; kb < 4; ++kb) {
#pragma unroll
      for (int j = 0; j < 8; ++j) {
        const int k = kb*32 + quad*8 + j;
        BwL[kb][j] = (short)f2bf(w[k*EMB + n0i]);
        BwH[kb][j] = (short)f2bf(w[k*EMB + 16 + n0i]);
      }
    }
    f32x4 accL = {0.f,0.f,0.f,0.f};
    f32x4 accH = {0.f,0.f,0.f,0.f};
#pragma unroll
    for (int kb = 0; kb < 4; ++kb) {
      bf16x8 A;
      A[0] = (short)f2bf(xa[kb].x); A[1] = (short)f2bf(xa[kb].y);
      A[2] = (short)f2bf(xa[kb].z); A[3] = (short)f2bf(xa[kb].w);
      A[4] = (short)f2bf(xb[kb].x); A[5] = (short)f2bf(xb[kb].y);
      A[6] = (short)f2bf(xb[kb].z); A[7] = (short)f2bf(xb[kb].w);
      accL = __builtin_amdgcn_mfma_f32_16x16x32_bf16(A, BwL[kb], accL, 0, 0, 0);
      accH = __builtin_amdgcn_mfma_f32_16x16x32_bf16(A, BwH[kb], accH, 0, 0, 0);
    }
    // bias + h store (f32) + LDS stash (bf16) for the p/q matmuls
    const float bL = b[n0i], bH = b[16 + n0i];
#pragma unroll
    for (int r = 0; r < 4; ++r) {
      const int row = quad*4 + r;
      const float vL = accL[r] + bL;
      const float vH = accH[r] + bH;
      h[(size_t)(r0 + row)*EMB + n0i]      = vL;
      h[(size_t)(r0 + row)*EMB + 16 + n0i] = vH;
      lds_hb[wv][row*HSTRIDE + n0i]      = f2bf(vL);
      lds_hb[wv][row*HSTRIDE + 16 + n0i] = f2bf(vH);
    }
    // A2 from LDS (wave-private; DS ops wave-ordered, no barrier)
    bf16x8 A2;
#pragma unroll
    for (int j = 0; j < 8; ++j)
      A2[j] = (short)lds_hb[wv][n0i*HSTRIDE + quad*8 + j];
    // B frags for p (w1 rows 0..31) and q (rows 32..63)
    bf16x8 BpL, BpH, BqL, BqH;
#pragma unroll
    for (int j = 0; j < 8; ++j) {
      const int k = quad*8 + j;
      BpL[j] = (short)f2bf(w1[k*EMB + n0i]);
      BpH[j] = (short)f2bf(w1[k*EMB + 16 + n0i]);
      BqL[j] = (short)f2bf(w1[(EMB + k)*EMB + n0i]);
      BqH[j] = (short)f2bf(w1[(EMB + k)*EMB + 16 + n0i]);
    }
    const f32x4 z4 = {0.f,0.f,0.f,0.f};
    f32x4 pL = __builtin_amdgcn_mfma_f32_16x16x32_bf16(A2, BpL, z4, 0, 0, 0);
    f32x4 pH = __builtin_amdgcn_mfma_f32_16x16x32_bf16(A2, BpH, z4, 0, 0, 0);
    f32x4 qL = __builtin_amdgcn_mfma_f32_16x16x32_bf16(A2, BqL, z4, 0, 0, 0);
    f32x4 qH = __builtin_amdgcn_mfma_f32_16x16x32_bf16(A2, BqH, z4, 0, 0, 0);
    // p: fold b1, repack via LDS, 16B stores
    const float b1L = b1[n0i], b1H = b1[16 + n0i];
#pragma unroll
    for (int r = 0; r < 4; ++r) {
      const int row = quad*4 + r;
      lds_pq[wv][row*HSTRIDE + n0i]      = f2bf(pL[r] + b1L);
      lds_pq[wv][row*HSTRIDE + 16 + n0i] = f2bf(pH[r] + b1H);
    }
    {
      const int row2 = lane >> 2;
      const int c8   = (lane & 3)*8;
      const uint4 ov = *(const uint4*)&lds_pq[wv][row2*HSTRIDE + c8];
      *(uint4*)(p + (size_t)(r0 + row2)*EMB + c8) = ov;
    }
    // q: same tile reused (wave-ordered DS)
#pragma unroll
    for (int r = 0; r < 4; ++r) {
      const int row = quad*4 + r;
      lds_pq[wv][row*HSTRIDE + n0i]      = f2bf(qL[r]);
      lds_pq[wv][row*HSTRIDE + 16 + n0i] = f2bf(qH[r]);
    }
    {
      const int row2 = lane >> 2;
      const int c8   = (lane & 3)*8;
      const uint4 ov = *(const uint4*)&lds_pq[wv][row2*HSTRIDE + c8];
      *(uint4*)(q + (size_t)(r0 + row2)*EMB + c8) = ov;
    }
  }
  // fused tail: histogram + EDGE-ORDER rec build (all coalesced)
  for (int e = blockIdx.x*256 + threadIdx.x; e < N_EDGES; e += gridDim.x*256) {
    const int s = ei[e];
    const int d = ei[N_EDGES + e];
    atomicAdd(&cnt[d], 1);
    const float4 v0 = ((const float4*)(ea + (size_t)e*ED))[0];
    const float4 v1 = ((const float4*)(ea + (size_t)e*ED))[1];
    const float ev[8] = {v0.x, v0.y, v0.z, v0.w, v1.x, v1.y, v1.z, v1.w};
    unsigned u[4];
#pragma unroll
    for (int j = 0; j < 4; ++j)
      u[j] = (unsigned)f2bf(ev[2*j]) | ((unsigned)f2bf(ev[2*j+1]) << 16);
    uint4* rp = rec + (size_t)e*2;
    rp[0] = make_uint4((unsigned)s, (unsigned)d, u[0], u[1]);
    rp[1] = make_uint4(u[2], u[3], 0u, 0u);
  }
}

// ---------------- CSR build ----------------
__global__ __launch_bounds__(256) void k_scan_a(const int* __restrict__ cnt,
                                                int* __restrict__ row_ptr, int* __restrict__ bsum) {
  __shared__ int s[256];
  const int gid = blockIdx.x*256 + threadIdx.x;
  const int v = (gid < N_NODES) ? cnt[gid] : 0;
  s[threadIdx.x] = v;
  __syncthreads();
  for (int o = 1; o < 256; o <<= 1) {
    const int t = (threadIdx.x >= o) ? s[threadIdx.x - o] : 0;
    __syncthreads();
    s[threadIdx.x] += t;
    __syncthreads();
  }
  if (gid < N_NODES) row_ptr[gid] = s[threadIdx.x] - v;
  if (threadIdx.x == 255) bsum[blockIdx.x] = s[255];
}

// fused scan_b+c: every block redundantly scans the 196 block sums, adds its offset
__global__ __launch_bounds__(256) void k_scan_bc(int* __restrict__ row_ptr,
                                                 const int* __restrict__ bsum) {
  __shared__ int s[256];
  const int t = threadIdx.x;
  const int v = (t < NODE_GRID) ? bsum[t] : 0;
  s[t] = v;
  __syncthreads();
  for (int o = 1; o < 256; o <<= 1) {
    const int tt = (t >= o) ? s[t - o] : 0;
    __syncthreads();
    s[t] += tt;
    __syncthreads();
  }
  const int off = (blockIdx.x == 0) ? 0 : s[blockIdx.x - 1];
  const int gid = blockIdx.x*256 + t;
  if (gid < N_NODES) row_ptr[gid] += off;
  if (blockIdx.x == 0 && t == 0) row_ptr[N_NODES] = N_EDGES;
}

// place: CSR slot assignment only. Payload stays in edge order; the only scattered
// store is a 4B edge id into the 3.2MB inv array (lines fill up in L2 -> cheap writeback).
__global__ __launch_bounds__(256) void k_place(
    const int* __restrict__ ei, const int* __restrict__ row_ptr, int* __restrict__ cnt2,
    int* __restrict__ inv)
{
  const int e = blockIdx.x*256 + threadIdx.x;  // grid 3125 exact
  const int d = ei[N_EDGES + e];
  const int pos = row_ptr[d] + atomicAdd(&cnt2[d], 1);
  inv[pos] = e;
}

// ---------------- edge kernels (y1 is never materialized in HBM) ----------------
// y1 tile recompute idiom (16 edges):
//   A-frag = ea (bf16, K=8 in quad 0, zero-padded to 32); B = W1b (quad 0 rows).
//   D = mfma(A,B) scattered to f32 LDS tile (stride 33, conflict-free re-read).
//   Reader lane (m=lane&15, quad): row m cols quad*8..+7; p[dst]/q[src] added via
//   coalesced 16B gathers (4 quads = one 64B row). Round to bf16 once.
// k_stats1 and k_msg2 share this exact value path => identical bf16 values.
// rec/y are in EDGE order (order-agnostic for sums/maps); only aggr uses inv.

// k_stats1: ALL rec loads + gathers for the wave's 4 tiles hoisted up front
// (12 independent global loads in flight), then compute.
__global__ __launch_bounds__(256) void k_stats1(
    const unsigned short* __restrict__ pb, const unsigned short* __restrict__ qb,
    const uint4* __restrict__ rec, const float* __restrict__ w1b,
    float* __restrict__ stats)
{
  __shared__ float lds_d[4][16*33];
  __shared__ float lds_s[4][32], lds_q[4][32];
  const int lane = threadIdx.x & 63;
  const int wv   = threadIdx.x >> 6;
  const int l15  = lane & 15;
  const int quad = lane >> 4;

  // B frags for W1b (8x32), K zero-padded: nonzero only in quad 0
  bf16x8 B1lo = {}, B1hi = {};
  if (quad == 0) {
#pragma unroll
    for (int j = 0; j < 8; ++j) {
      B1lo[j] = (short)f2bf(w1b[j*EMB + l15]);
      B1hi[j] = (short)f2bf(w1b[j*EMB + 16 + l15]);
    }
  }

  const int tile0 = blockIdx.x * (4*ST_TPW);
  uint4 RA[ST_TPW], RB[ST_TPW];
#pragma unroll
  for (int t = 0; t < ST_TPW; ++t) {
    const int tile = tile0 + t*4 + wv;           // exact: 0..49999
    const size_t e0 = (size_t)tile * 16;
    const uint4* r4 = rec + (e0 + l15)*2;
    RA[t] = r4[0];
    RB[t] = (quad == 0) ? r4[1] : make_uint4(0u,0u,0u,0u);
  }
  uint4 PG[ST_TPW], QG[ST_TPW];
#pragma unroll
  for (int t = 0; t < ST_TPW; ++t) {
    PG[t] = *(const uint4*)(pb + (size_t)RA[t].y*EMB + quad*8);
    QG[t] = *(const uint4*)(qb + (size_t)RA[t].x*EMB + quad*8);
  }

  float ts[8], tss[8];
#pragma unroll
  for (int j = 0; j < 8; ++j) { ts[j] = 0.f; tss[j] = 0.f; }

#pragma unroll
  for (int t = 0; t < ST_TPW; ++t) {
    bf16x8 A = {};
    if (quad == 0) {
      A[0] = (short)(RA[t].z & 0xFFFFu); A[1] = (short)(RA[t].z >> 16);
      A[2] = (short)(RA[t].w & 0xFFFFu); A[3] = (short)(RA[t].w >> 16);
      A[4] = (short)(RB[t].x & 0xFFFFu); A[5] = (short)(RB[t].x >> 16);
      A[6] = (short)(RB[t].y & 0xFFFFu); A[7] = (short)(RB[t].y >> 16);
    }
    const f32x4 z4 = {0.f,0.f,0.f,0.f};
    f32x4 D0 = __builtin_amdgcn_mfma_f32_16x16x32_bf16(A, B1lo, z4, 0, 0, 0);
    f32x4 D1 = __builtin_amdgcn_mfma_f32_16x16x32_bf16(A, B1hi, z4, 0, 0, 0);
#pragma unroll
    for (int r = 0; r < 4; ++r) {
      const int row = quad*4 + r;
      lds_d[wv][row*33 + l15]      = D0[r];
      lds_d[wv][row*33 + 16 + l15] = D1[r];
    }
    const unsigned pu[4] = {PG[t].x, PG[t].y, PG[t].z, PG[t].w};
    const unsigned qu[4] = {QG[t].x, QG[t].y, QG[t].z, QG[t].w};
#pragma unroll
    for (int jj = 0; jj < 4; ++jj) {
      const float d0 = lds_d[wv][l15*33 + quad*8 + 2*jj];
      const float d1 = lds_d[wv][l15*33 + quad*8 + 2*jj + 1];
      const float v0 = (d0 + bf2f((unsigned short)(pu[jj] & 0xFFFFu)))
                            + bf2f((unsigned short)(qu[jj] & 0xFFFFu));
      const float v1 = (d1 + bf2f((unsigned short)(pu[jj] >> 16)))
                            + bf2f((unsigned short)(qu[jj] >> 16));
      const float w0 = bf2f(f2bf(v0));
      const float w1v = bf2f(f2bf(v1));
      ts[2*jj]   += w0;  tss[2*jj]   = fmaf(w0, w0, tss[2*jj]);
      ts[2*jj+1] += w1v; tss[2*jj+1] = fmaf(w1v, w1v, tss[2*jj+1]);
    }
  }

  // reduce over l15 (lanes in a quad share the same col set quad*8+j)
#pragma unroll
  for (int j = 0; j < 8; ++j) {
    float a = ts[j], b = tss[j];
#pragma unroll
    for (int o = 1; o < 16; o <<= 1) {
      a += __shfl_xor(a, o, 64);
      b += __shfl_xor(b, o, 64);
    }
    ts[j] = a; tss[j] = b;
  }
  if (l15 == 0) {
#pragma unroll
    for (int j = 0; j < 8; ++j) {
      lds_s[wv][quad*8 + j] = ts[j];
      lds_q[wv][quad*8 + j] = tss[j];
    }
  }
  __syncthreads();
  if (threadIdx.x < 64) {
    const int c = threadIdx.x & 31;
    const int kind = threadIdx.x >> 5;
    float v = 0.f;
#pragma unroll
    for (int wq = 0; wq < 4; ++wq)
      v += kind ? lds_q[wq][c] : lds_s[wq][c];
    atomicAdd(stats + ((blockIdx.x & (SREP-1)) << 6) + kind*32 + c, v);
  }
}

// Fused msg1+msg2: recompute y1 per tile, bn1+relu in-register, W2 MFMA,
// write y2 only; stats2. Rotating 1-deep prefetch of next tile's rec + gathers.
__global__ __launch_bounds__(256) void k_msg2(
    const unsigned short* __restrict__ pb, const unsigned short* __restrict__ qb,
    const uint4* __restrict__ rec, const float* __restrict__ w1b,
    const float* __restrict__ stats1, const float* __restrict__ g1, const float* __restrict__ be1,
    const float* __restrict__ w2, const float* __restrict__ b2,
    unsigned short* __restrict__ y, float* __restrict__ stats2)
{
  __shared__ float lds_d[4][16*33];
  __shared__ __align__(16) unsigned short lds_t[4][16*32];
  __shared__ float lds_s[4][32], lds_q[4][32];
  __shared__ float cf[64];

  coef_from_stats(stats1, g1, be1, 1.0f/(float)N_EDGES, cf);

  const int lane = threadIdx.x & 63;
  const int wv   = threadIdx.x >> 6;
  const int l15  = lane & 15;
  const int quad = lane >> 4;

  bf16x8 B1lo = {}, B1hi = {};
  if (quad == 0) {
#pragma unroll
    for (int j = 0; j < 8; ++j) {
      B1lo[j] = (short)f2bf(w1b[j*EMB + l15]);
      B1hi[j] = (short)f2bf(w1b[j*EMB + 16 + l15]);
    }
  }
  bf16x8 Blo, Bhi;   // W2 (32x32)
#pragma unroll
  for (int j = 0; j < 8; ++j) {
    Blo[j] = (short)f2bf(w2[(quad*8 + j)*EMB + l15]);
    Bhi[j] = (short)f2bf(w2[(quad*8 + j)*EMB + 16 + l15]);
  }
  float a1[8], c1[8];
#pragma unroll
  for (int j = 0; j < 8; ++j) {
    a1[j] = cf[quad*8 + j];
    c1[j] = cf[EMB + quad*8 + j];
  }
  const float b2c0 = b2[l15], b2c1 = b2[16 + l15];

  float ts[8], tss[8];
#pragma unroll
  for (int j = 0; j < 8; ++j) { ts[j] = 0.f; tss[j] = 0.f; }

  const int tile0 = blockIdx.x * (4*MSG2_TPW);

  // prologue: tile 0 rec + gathers
  uint4 cRA, cRB, cPG, cQG;
  {
    const size_t e0 = (size_t)(tile0 + wv) * 16;
    const uint4* r4 = rec + (e0 + l15)*2;
    cRA = r4[0];
    cRB = (quad == 0) ? r4[1] : make_uint4(0u,0u,0u,0u);
    cPG = *(const uint4*)(pb + (size_t)cRA.y*EMB + quad*8);
    cQG = *(const uint4*)(qb + (size_t)cRA.x*EMB + quad*8);
  }

#pragma unroll
  for (int t = 0; t < MSG2_TPW; ++t) {
    const size_t e0 = (size_t)(tile0 + t*4 + wv) * 16;

    // issue next tile's rec load before current compute
    uint4 nRA = make_uint4(0u,0u,0u,0u), nRB = make_uint4(0u,0u,0u,0u);
    uint4 nPG = make_uint4(0u,0u,0u,0u), nQG = make_uint4(0u,0u,0u,0u);
    if (t + 1 < MSG2_TPW) {
      const size_t e1 = (size_t)(tile0 + (t+1)*4 + wv) * 16;
      const uint4* r4 = rec + (e1 + l15)*2;
      nRA = r4[0];
      nRB = (quad == 0) ? r4[1] : make_uint4(0u,0u,0u,0u);
    }

    // phase 1: y1 partial via MFMA on ea
    bf16x8 A = {};
    if (quad == 0) {
      A[0] = (short)(cRA.z & 0xFFFFu); A[1] = (short)(cRA.z >> 16);
      A[2] = (short)(cRA.w & 0xFFFFu); A[3] = (short)(cRA.w >> 16);
      A[4] = (short)(cRB.x & 0xFFFFu); A[5] = (short)(cRB.x >> 16);
      A[6] = (short)(cRB.y & 0xFFFFu); A[7] = (short)(cRB.y >> 16);
    }
    const f32x4 z4 = {0.f,0.f,0.f,0.f};
    f32x4 D0 = __builtin_amdgcn_mfma_f32_16x16x32_bf16(A, B1lo, z4, 0, 0, 0);
    f32x4 D1 = __builtin_amdgcn_mfma_f32_16x16x32_bf16(A, B1hi, z4, 0, 0, 0);
#pragma unroll
    for (int r = 0; r < 4; ++r) {
      const int row = quad*4 + r;
      lds_d[wv][row*33 + l15]      = D0[r];
      lds_d[wv][row*33 + 16 + l15] = D1[r];
    }

    // issue next tile's gathers (dep on nRA) mid-body
    if (t + 1 < MSG2_TPW) {
      nPG = *(const uint4*)(pb + (size_t)nRA.y*EMB + quad*8);
      nQG = *(const uint4*)(qb + (size_t)nRA.x*EMB + quad*8);
    }

    // phase 2: combine + bn1 + relu + W2 MFMA + store
    const unsigned pu[4] = {cPG.x, cPG.y, cPG.z, cPG.w};
    const unsigned qu[4] = {cQG.x, cQG.y, cQG.z, cQG.w};
    bf16x8 A2;
#pragma unroll
    for (int jj = 0; jj < 4; ++jj) {
      const float d0 = lds_d[wv][l15*33 + quad*8 + 2*jj];
      const float d1 = lds_d[wv][l15*33 + quad*8 + 2*jj + 1];
      const float v0 = (d0 + bf2f((unsigned short)(pu[jj] & 0xFFFFu)))
                            + bf2f((unsigned short)(qu[jj] & 0xFFFFu));
      const float v1 = (d1 + bf2f((unsigned short)(pu[jj] >> 16)))
                            + bf2f((unsigned short)(qu[jj] >> 16));
      const float w0 = bf2f(f2bf(v0));
      const float w1v = bf2f(f2bf(v1));
      const float r0 = fmaxf(fmaf(a1[2*jj],   w0,  c1[2*jj]),   0.f);
      const float r1 = fmaxf(fmaf(a1[2*jj+1], w1v, c1[2*jj+1]), 0.f);
      A2[2*jj]   = (short)f2bf(r0);
      A2[2*jj+1] = (short)f2bf(r1);
    }

    f32x4 acc0 = {0.f, 0.f, 0.f, 0.f};
    f32x4 acc1 = {0.f, 0.f, 0.f, 0.f};
    acc0 = __builtin_amdgcn_mfma_f32_16x16x32_bf16(A2, Blo, acc0, 0, 0, 0);
    acc1 = __builtin_amdgcn_mfma_f32_16x16x32_bf16(A2, Bhi, acc1, 0, 0, 0);

#pragma unroll
    for (int r = 0; r < 4; ++r) {
      const int row = quad*4 + r;
      lds_t[wv][row*32 + l15]      = f2bf(acc0[r] + b2c0);
      lds_t[wv][row*32 + 16 + l15] = f2bf(acc1[r] + b2c1);
    }
    const uint4 orow = *(const uint4*)&lds_t[wv][(lane>>2)*32 + (lane&3)*8];
    *(uint4*)(y + (e0 + (lane>>2))*EMB + (lane&3)*8) = orow;

    const unsigned uo[4] = {orow.x, orow.y, orow.z, orow.w};
#pragma unroll
    for (int j = 0; j < 4; ++j) {
      const float v0 = bf2f((unsigned short)(uo[j] & 0xFFFFu));
      const float v1 = bf2f((unsigned short)(uo[j] >> 16));
      ts[2*j]   += v0;  tss[2*j]   = fmaf(v0, v0, tss[2*j]);
      ts[2*j+1] += v1;  tss[2*j+1] = fmaf(v1, v1, tss[2*j+1]);
    }

    cRA = nRA; cRB = nRB; cPG = nPG; cQG = nQG;
  }

  // stats2: lane's cols are (lane&3)*8+j -> reduce over lane>>2
#pragma unroll
  for (int j = 0; j < 8; ++j) {
    float s = ts[j], qq = tss[j];
#pragma unroll
    for (int o = 4; o < 64; o <<= 1) {
      s  += __shfl_xor(s, o, 64);
      qq += __shfl_xor(qq, o, 64);
    }
    ts[j] = s; tss[j] = qq;
  }
  if (lane < 4) {
#pragma unroll
    for (int j = 0; j < 8; ++j) {
      lds_s[wv][lane*8 + j] = ts[j];
      lds_q[wv][lane*8 + j] = tss[j];
    }
  }
  __syncthreads();
  if (threadIdx.x < 64) {
    const int c = threadIdx.x & 31;
    const int kind = threadIdx.x >> 5;
    float v = 0.f;
#pragma unroll
    for (int wq = 0; wq < 4; ++wq)
      v += kind ? lds_q[wq][c] : lds_s[wq][c];
    atomicAdd(stats2 + ((blockIdx.x & (SREP-1)) << 6) + kind*32 + c, v);
  }
}

// fused aggr + upd1: aggr lives in LDS only; z1 = concat(h,aggr)@uw1+b; stats.
// Aggregation: CSR slots -> inv (coalesced 4B) -> y row (random 64B line, L2/L3-hot).
// Lane loads uint4 (8 bf16 cols), 4 lanes/row -> 8 rows/iter in flight.
__global__ __launch_bounds__(256) void k_aggr_upd1(
    const unsigned short* __restrict__ y, const int* __restrict__ row_ptr,
    const int* __restrict__ inv,
    const float* __restrict__ h,
    const float* __restrict__ stats1, const float* __restrict__ g2, const float* __restrict__ be2,
    const float* __restrict__ uw1, const float* __restrict__ ub1,
    float* __restrict__ z, float* __restrict__ stats2)
{
  __shared__ float cf[64];
  __shared__ float lh[8][32];
  __shared__ float la[8][32];
  __shared__ float rs[4][32], rq[4][32];
  coef_from_stats(stats1, g2, be2, 1.0f/(float)N_EDGES, cf);

  const int g = threadIdx.x >> 5;
  const int l = threadIdx.x & 31;
  const int n = blockIdx.x*8 + g;   // grid 6250 exact -> n < N_NODES always

  // stage h row into LDS (coalesced)
  lh[g][l] = h[(size_t)n*EMB + l];

  // aggregation: 8 rows/iter, lane covers cols c8..c8+7
  const int c8  = (l & 3) * 8;
  const int rof = l >> 2;          // 0..7
  float a[8], b[8];
#pragma unroll
  for (int j = 0; j < 8; ++j) { a[j] = cf[c8 + j]; b[j] = cf[EMB + c8 + j]; }
  const int lo = row_ptr[n], hi = row_ptr[n+1];
  float acc[8];
#pragma unroll
  for (int j = 0; j < 8; ++j) acc[j] = 0.f;
  for (int r = lo + rof; r < hi; r += 8) {
    const int ee = inv[r];
    const uint4 u = *(const uint4*)(y + (size_t)ee*EMB + c8);
    const unsigned uu[4] = {u.x, u.y, u.z, u.w};
#pragma unroll
    for (int t = 0; t < 4; ++t) {
      const float v0 = bf2f((unsigned short)(uu[t] & 0xFFFFu));
      const float v1 = bf2f((unsigned short)(uu[t] >> 16));
      acc[2*t]   += fmaxf(fmaf(a[2*t],   v0, b[2*t]),   0.f);
      acc[2*t+1] += fmaxf(fmaf(a[2*t+1], v1, b[2*t+1]), 0.f);
    }
  }
  // reduce over rof (xor 4/8/16 stays within each 32-lane half)
#pragma unroll
  for (int j = 0; j < 8; ++j) {
    float v = acc[j];
    v += __shfl_xor(v, 4, 64);
    v += __shfl_xor(v, 8, 64);
    v += __shfl_xor(v, 16, 64);
    acc[j] = v;
  }
  if (rof == 0) {
#pragma unroll
    for (int j = 0; j < 8; ++j) la[g][c8 + j] = acc[j];
  }
  __syncthreads();

  // upd1: col l of node n
  float accu = ub1[l];
#pragma unroll
  for (int k = 0; k < EMB; ++k) accu = fmaf(lh[g][k], uw1[k*EMB + l], accu);
#pragma unroll
  for (int k = 0; k < EMB; ++k) accu = fmaf(la[g][k], uw1[(EMB + k)*EMB + l], accu);
  z[(size_t)n*EMB + l] = accu;

  // stats
  const float sq = accu*accu;
  const float a2 = accu + __shfl_down(accu, 32, 64);
  const float q2 = sq   + __shfl_down(sq,   32, 64);
  const int wv = threadIdx.x >> 6;
  if ((threadIdx.x & 63) < 32) { rs[wv][l] = a2; rq[wv][l] = q2; }
  __syncthreads();
  if (threadIdx.x < 64) {
    const int c = threadIdx.x & 31;
    const int kind = threadIdx.x >> 5;
    float v = 0.f;
#pragma unroll
    for (int wq = 0; wq < 4; ++wq)
      v += kind ? rq[wq][c] : rs[wq][c];
    atomicAdd(stats2 + ((blockIdx.x & (SREP-1)) << 6) + kind*32 + c, v);
  }
}

// z2 = relu(bn(z1)) @ uw2 + b, in place on z; coef inline; stats. (4-wave col-split)
__global__ __launch_bounds__(256) void k_upd2(
    float* __restrict__ z,
    const float* __restrict__ stats1, const float* __restrict__ g1, const float* __restrict__ be1,
    const float* __restrict__ w, const float* __restrict__ b,
    float* __restrict__ stats2)
{
  __shared__ float cf[64];
  __shared__ float lds_s[32], lds_q[32];
  coef_from_stats(stats1, g1, be1, 1.0f/(float)N_NODES, cf);

  const int lane = threadIdx.x & 63;
  const int wv   = threadIdx.x >> 6;
  const int n  = blockIdx.x*64 + lane;
  const int c0 = wv*8;
  float acc[8];
#pragma unroll
  for (int j = 0; j < 8; ++j) acc[j] = 0.f;
  if (n < N_NODES) {
#pragma unroll
    for (int j = 0; j < 8; ++j) acc[j] = b[c0 + j];
    const float4* zp = (const float4*)(z + (size_t)n*EMB);
#pragma unroll
    for (int k4 = 0; k4 < 8; ++k4) {
      const float4 v = zp[k4];
      const float mv[4] = {v.x, v.y, v.z, v.w};
#pragma unroll
      for (int t = 0; t < 4; ++t) {
        const int k = 4*k4 + t;
        const float m = fmaxf(fmaf(cf[k], mv[t], cf[EMB + k]), 0.f);
        const float* wk = w + k*EMB + c0;
#pragma unroll
        for (int j = 0; j < 8; ++j) acc[j] = fmaf(m, wk[j], acc[j]);
      }
    }
  }
  float ts[8], tss[8];
#pragma unroll
  for (int j = 0; j < 8; ++j) { ts[j] = acc[j]; tss[j] = acc[j]*acc[j]; }
  wave_stats_atomic(ts, tss, lds_s, lds_q, stats2);  // barrier inside
  if (n < N_NODES) {
    float4 o0, o1;
    o0.x = acc[0]; o0.y = acc[1]; o0.z = acc[2]; o0.w = acc[3];
    o1.x = acc[4]; o1.y = acc[5]; o1.z = acc[6]; o1.w = acc[7];
    *(float4*)(z + (size_t)n*EMB + c0)     = o0;
    *(float4*)(z + (size_t)n*EMB + c0 + 4) = o1;
  }
}

// h += relu(bn(z2)); p/q (bf16, b1_next folded into p) via LDS hn-exchange.
__global__ __launch_bounds__(256) void k_resid_pq(
    float* __restrict__ h, const float* __restrict__ z,
    const float* __restrict__ stats, const float* __restrict__ g, const float* __restrict__ be,
    const float* __restrict__ w1_next, const float* __restrict__ b1_next,
    unsigned short* __restrict__ p, unsigned short* __restrict__ q)
{
  __shared__ float cf[64];
  __shared__ float lds_h[64][33];
  coef_from_stats(stats, g, be, 1.0f/(float)N_NODES, cf);

  const int lane = threadIdx.x & 63;
  const int wv   = threadIdx.x >> 6;
  const int n  = blockIdx.x*64 + lane;
  const int c0 = wv*8;
  if (n < N_NODES) {
    const float4* zp = (const float4*)(z + (size_t)n*EMB + c0);
    float4* hp = (float4*)(h + (size_t)n*EMB + c0);
    float hn[8];
    const float4 z0 = zp[0], z1 = zp[1];
    const float4 h0 = hp[0], h1 = hp[1];
    const float zv[8] = {z0.x, z0.y, z0.z, z0.w, z1.x, z1.y, z1.z, z1.w};
    const float hv[8] = {h0.x, h0.y, h0.z, h0.w, h1.x, h1.y, h1.z, h1.w};
#pragma unroll
    for (int j = 0; j < 8; ++j) {
      const int k = c0 + j;
      hn[j] = hv[j] + fmaxf(fmaf(cf[k], zv[j], cf[EMB + k]), 0.f);
      lds_h[lane][k] = hn[j];
    }
    float4 o0, o1;
    o0.x = hn[0]; o0.y = hn[1]; o0.z = hn[2]; o0.w = hn[3];
    o1.x = hn[4]; o1.y = hn[5]; o1.z = hn[6]; o1.w = hn[7];
    hp[0] = o0; hp[1] = o1;
  }
  __syncthreads();
  if (n < N_NODES && w1_next) {
    float ap[8], aq[8];
#pragma unroll
    for (int j = 0; j < 8; ++j) { ap[j] = b1_next[c0 + j]; aq[j] = 0.f; }
#pragma unroll
    for (int k = 0; k < EMB; ++k) {
      const float hvv = lds_h[lane][k];
      const float* wp = w1_next + k*EMB + c0;
      const float* wq = w1_next + (EMB + k)*EMB + c0;
#pragma unroll
      for (int j = 0; j < 8; ++j) ap[j] = fmaf(hvv, wp[j], ap[j]);
#pragma unroll
      for (int j = 0; j < 8; ++j) aq[j] = fmaf(hvv, wq[j], aq[j]);
    }
    unsigned up[4], uq[4];
#pragma unroll
    for (int j = 0; j < 4; ++j) {
      up[j] = (unsigned)f2bf(ap[2*j]) | ((unsigned)f2bf(ap[2*j+1]) << 16);
      uq[j] = (unsigned)f2bf(aq[2*j]) | ((unsigned)f2bf(aq[2*j+1]) << 16);
    }
    uint4 op; op.x = up[0]; op.y = up[1]; op.z = up[2]; op.w = up[3];
    uint4 oq; oq.x = uq[0]; oq.y = uq[1]; oq.z = uq[2]; oq.w = uq[3];
    *(uint4*)(p + (size_t)n*EMB + c0) = op;
    *(uint4*)(q + (size_t)n*EMB + c0) = oq;
  }
}

// per-graph mean pool + final linear
__global__ void k_pool(const float* __restrict__ h, const int* __restrict__ batch,
                       const float* __restrict__ pw, const float* __restrict__ pb,
                       float* __restrict__ out)
{
  __shared__ float sred[256];
  __shared__ float hg[EMB];
  const int b = blockIdx.x;
  int lo = 0, hi = N_NODES;
  while (lo < hi) { int m = (lo + hi) >> 1; if (batch[m] < b) lo = m + 1; else hi = m; }
  const int start = lo;
  hi = N_NODES;
  while (lo < hi) { int m = (lo + hi) >> 1; if (batch[m] < b + 1) lo = m + 1; else hi = m; }
  const int end = lo;

  const int c = threadIdx.x & (EMB-1);
  const int r = threadIdx.x >> 5;
  float s = 0.f;
  for (int n = start + r; n < end; n += 8) s += h[(size_t)n*EMB + c];
  sred[threadIdx.x] = s;
  __syncthreads();
  if (threadIdx.x < EMB) {
    float tot = 0.f;
#pragma unroll
    for (int r2 = 0; r2 < 8; ++r2) tot += sred[r2*EMB + threadIdx.x];
    const float cnt = (float)(end - start);
    hg[threadIdx.x] = tot / fmaxf(cnt, 1.f);
  }
  __syncthreads();
  if (threadIdx.x < OUTD) {
    float acc = pb[threadIdx.x];
#pragma unroll
    for (int cc = 0; cc < EMB; ++cc) acc = fmaf(hg[cc], pw[cc*OUTD + threadIdx.x], acc);
    out[b*OUTD + threadIdx.x] = acc;
  }
}

// ---------------- host ----------------

extern "C" void kernel_launch(void* const* d_in, const int* in_sizes, int n_in,
                              void* d_out, int out_size, void* d_ws, size_t ws_size,
                              hipStream_t stream) {
  const float* x        = (const float*)d_in[0];
  const int*   ei       = (const int*)  d_in[1];
  const float* ea       = (const float*)d_in[2];
  const int*   batch    = (const int*)  d_in[3];
  const float* lin_in_w = (const float*)d_in[4];
  const float* lin_in_b = (const float*)d_in[5];
  const float* msg_w1   = (const float*)d_in[6];
  const float* msg_b1   = (const float*)d_in[7];
  const float* msg_g1   = (const float*)d_in[8];
  const float* msg_be1  = (const float*)d_in[9];
  const float* msg_w2   = (const float*)d_in[10];
  const float* msg_b2   = (const float*)d_in[11];
  const float* msg_g2   = (const float*)d_in[12];
  const float* msg_be2  = (const float*)d_in[13];
  const float* upd_w1   = (const float*)d_in[14];
  const float* upd_b1   = (const float*)d_in[15];
  const float* upd_g1   = (const float*)d_in[16];
  const float* upd_be1  = (const float*)d_in[17];
  const float* upd_w2   = (const float*)d_in[18];
  const float* upd_b2   = (const float*)d_in[19];
  const float* upd_g2   = (const float*)d_in[20];
  const float* upd_be2  = (const float*)d_in[21];
  const float* pred_w   = (const float*)d_in[22];
  const float* pred_b   = (const float*)d_in[23];
  float* out = (float*)d_out;

  // Workspace layout (~100 MB)
  char* wsb = (char*)d_ws;
  unsigned short* y  = (unsigned short*)wsb;                            // E*32 bf16 (y2, edge order)
  uint4* rec = (uint4*)(wsb + (size_t)N_EDGES*EMB*2);                   // E x 32B records (edge order)
  unsigned short* p  = (unsigned short*)(rec + (size_t)N_EDGES*2);      // N*32 bf16
  unsigned short* q  = p + (size_t)N_NODES*EMB;                         // N*32 bf16
  float* h       = (float*)(q + (size_t)N_NODES*EMB);                   // N*32 f32
  float* z       = h + (size_t)N_NODES*EMB;                             // N*32 f32 (z1/z2 in place)
  float* stats   = z + (size_t)N_NODES*EMB;                             // 16 x SREP x 64
  int*   cnt     = (int*)(stats + 16*SREP*64);
  int*   cnt2    = cnt + N_NODES;
  int*   row_ptr = cnt2 + N_NODES;
  int*   bsum    = row_ptr + N_NODES + 1;
  int*   inv     = bsum + 256;                                          // E x 4B CSR->edge map
  const size_t need = ((size_t)((char*)(inv + N_EDGES) - wsb));
  if (ws_size < need) return;

  hipMemsetAsync(stats, 0, (16*SREP*64 + 2*N_NODES)*sizeof(float), stream);

  k_lin_in_pq<<<LIN_GRID, 256, 0, stream>>>(x, lin_in_w, lin_in_b, msg_w1, msg_b1, ei, ea,
                                            h, p, q, cnt, rec);
  k_scan_a<<<NODE_GRID, 256, 0, stream>>>(cnt, row_ptr, bsum);
  k_scan_bc<<<NODE_GRID, 256, 0, stream>>>(row_ptr, bsum);
  k_place<<<EDGE_GRID, 256, 0, stream>>>(ei, row_ptr, cnt2, inv);

  for (int l = 0; l < NLAYERS; ++l) {
    const int st = l*4;
    const float* w1  = msg_w1 + (size_t)l*(2*EMB+ED)*EMB;
    const float* w1b = w1 + (size_t)2*EMB*EMB;
    const float* w2  = msg_w2 + (size_t)l*EMB*EMB;
    const float* uw1 = upd_w1 + (size_t)l*(2*EMB)*EMB;
    const float* uw2 = upd_w2 + (size_t)l*EMB*EMB;
    const float* w1_next = (l+1 < NLAYERS) ? msg_w1 + (size_t)(l+1)*(2*EMB+ED)*EMB : nullptr;
    const float* b1_next = (l+1 < NLAYERS) ? msg_b1 + (size_t)(l+1)*EMB : nullptr;

    k_stats1<<<ST_GRID, 256, 0, stream>>>(p, q, rec, w1b, stats + (size_t)st*SREP*64);
    k_msg2<<<MSG2_GRID, 256, 0, stream>>>(p, q, rec, w1b,
                                          stats + (size_t)st*SREP*64,
                                          msg_g1 + l*EMB, msg_be1 + l*EMB,
                                          w2, msg_b2 + l*EMB,
                                          y, stats + (size_t)(st+1)*SREP*64);
    k_aggr_upd1<<<AU_GRID, 256, 0, stream>>>(y, row_ptr, inv, h,
                                             stats + (size_t)(st+1)*SREP*64,
                                             msg_g2 + l*EMB, msg_be2 + l*EMB,
                                             uw1, upd_b1 + l*EMB,
                                             z, stats + (size_t)(st+2)*SREP*64);
    k_upd2<<<NODE4_GRID, 256, 0, stream>>>(z, stats + (size_t)(st+2)*SREP*64,
                                           upd_g1 + l*EMB, upd_be1 + l*EMB,
                                           uw2, upd_b2 + l*EMB, stats + (size_t)(st+3)*SREP*64);
    k_resid_pq<<<NODE4_GRID, 256, 0, stream>>>(h, z, stats + (size_t)(st+3)*SREP*64,
                                               upd_g2 + l*EMB, upd_be2 + l*EMB,
                                               w1_next, b1_next, p, q);
  }

  k_pool<<<NB, 256, 0, stream>>>(h, batch, pred_w, pred_b, out);
}

// Round 10
// 800.693 us; speedup vs baseline: 1.0632x; 1.0632x over previous
//
#include <hip/hip_runtime.h>
#include <cstddef>

// Problem constants
#define N_NODES 50000
#define N_EDGES 800000
#define IN_DIM  128
#define EMB     32
#define ED      8
#define NLAYERS 4
#define NB      64
#define OUTD    10
#define EPS_BN  1e-5f

#define EDGE_GRID 3125   // 800000/256 exact
#define NODE_GRID 196    // ceil(50000/256)  (scan kernels)
#define NODE4_GRID 782   // ceil(50000/64)   (4-wave node kernels)
#define AU_GRID   6250   // 50000/8 (aggr+upd1)
#define NTILE_N   3125   // 50000/16 (lin_in tiles)
#define LIN_GRID  782    // ceil(3125/4)
#define ST_TPW    4
#define ST_GRID   3125   // 3125 blocks * 4 waves * 4 tiles * 16 edges = 800000 exact
#define MSG2_TPW  4
#define MSG2_GRID 3125   // same exact tiling

#define SREP 4           // stats replication; stage stride = SREP*64

typedef short bf16x8 __attribute__((ext_vector_type(8)));
typedef float f32x4  __attribute__((ext_vector_type(4)));

// ---------------- helpers ----------------

__device__ __forceinline__ unsigned short f2bf(float x) {
  union { float f; unsigned u; } v; v.f = x;
  unsigned b = v.u + 0x7FFFu + ((v.u >> 16) & 1u);
  return (unsigned short)(b >> 16);
}
__device__ __forceinline__ float bf2f(unsigned short s) {
  union { unsigned u; float f; } v; v.u = ((unsigned)s) << 16;
  return v.f;
}

// Inline BN-coef preamble from SREP-replicated stats: cf[c]=a, cf[32+c]=be-mu*a.
__device__ __forceinline__ void coef_from_stats(const float* __restrict__ stats_stage,
                                                const float* __restrict__ g,
                                                const float* __restrict__ be,
                                                float inv_count, float* __restrict__ cf) {
  if (threadIdx.x < EMB) {
    const int c = threadIdx.x;
    float s = 0.f, ss = 0.f;
#pragma unroll
    for (int r = 0; r < SREP; ++r) {
      s  += stats_stage[r*64 + c];
      ss += stats_stage[r*64 + EMB + c];
    }
    const float mu  = s * inv_count;
    const float var = ss * inv_count - mu*mu;
    const float a = g[c] * rsqrtf(var + EPS_BN);
    cf[c] = a;
    cf[EMB + c] = fmaf(-mu, a, be[c]);
  }
  __syncthreads();
}

// Per-wave stats (8 cols each, node kernels) -> LDS -> 64 atomics; has a barrier.
__device__ __forceinline__ void wave_stats_atomic(float ts[8], float tss[8],
                                                  float* __restrict__ lds_s,
                                                  float* __restrict__ lds_q,
                                                  float* __restrict__ stats_stage) {
  const int lane = threadIdx.x & 63;
  const int wv   = threadIdx.x >> 6;
#pragma unroll
  for (int j = 0; j < 8; ++j) {
    float a = ts[j], b = tss[j];
#pragma unroll
    for (int o = 32; o > 0; o >>= 1) {
      a += __shfl_down(a, o, 64);
      b += __shfl_down(b, o, 64);
    }
    ts[j] = a; tss[j] = b;
  }
  if (lane == 0) {
#pragma unroll
    for (int j = 0; j < 8; ++j) {
      lds_s[wv*8 + j] = ts[j];
      lds_q[wv*8 + j] = tss[j];
    }
  }
  __syncthreads();
  if (threadIdx.x < 64) {
    const float v = (threadIdx.x < 32) ? lds_s[threadIdx.x] : lds_q[threadIdx.x - 32];
    atomicAdd(stats_stage + ((blockIdx.x & (SREP-1)) << 6) + threadIdx.x, v);
  }
}

// ---------------- lin_in + p/q via MFMA (one 16-node tile per wave) ----------------
// Fused tail: histogram atomic ALSO yields the edge's within-node rank (one RMW
// for both) — rank stored coalesced; k_place_scatter then needs NO atomics.
#define HSTRIDE 40  // bf16 LDS tile row stride (16B-aligned, conflict-benign)

__global__ __launch_bounds__(256) void k_lin_in_pq(
    const float* __restrict__ x, const float* __restrict__ w, const float* __restrict__ b,
    const float* __restrict__ w1, const float* __restrict__ b1, const int* __restrict__ ei,
    float* __restrict__ h, unsigned short* __restrict__ p, unsigned short* __restrict__ q,
    int* __restrict__ cnt, int* __restrict__ rankp)
{
  __shared__ __align__(16) unsigned short lds_hb[4][16*HSTRIDE];
  __shared__ __align__(16) unsigned short lds_pq[4][16*HSTRIDE];
  const int lane = threadIdx.x & 63;
  const int wv   = threadIdx.x >> 6;
  const int n0i  = lane & 15;
  const int quad = lane >> 4;

  const int tile = blockIdx.x*4 + wv;
  if (tile < NTILE_N) {
    const int r0 = tile*16;
    // issue all x loads first (8 independent float4s in flight during w loads)
    float4 xa[4], xb[4];
#pragma unroll
    for (int kb = 0; kb < 4; ++kb) {
      xa[kb] = *(const float4*)(x + (size_t)(r0 + n0i)*IN_DIM + kb*32 + quad*8);
      xb[kb] = *(const float4*)(x + (size_t)(r0 + n0i)*IN_DIM + kb*32 + quad*8 + 4);
    }
    // B frags for lin_in W (128x32 f32, row-major) — 4 k-blocks x {lo,hi}
    bf16x8 BwL[4], BwH[4];
#pragma unroll
    for (int kb = 0; kb < 4; ++kb) {
#pragma unroll
      for (int j = 0; j < 8; ++j) {
        const int k = kb*32 + quad*8 + j;
        BwL[kb][j] = (short)f2bf(w[k*EMB + n0i]);
        BwH[kb][j] = (short)f2bf(w[k*EMB + 16 + n0i]);
      }
    }
    f32x4 accL = {0.f,0.f,0.f,0.f};
    f32x4 accH = {0.f,0.f,0.f,0.f};
#pragma unroll
    for (int kb = 0; kb < 4; ++kb) {
      bf16x8 A;
      A[0] = (short)f2bf(xa[kb].x); A[1] = (short)f2bf(xa[kb].y);
      A[2] = (short)f2bf(xa[kb].z); A[3] = (short)f2bf(xa[kb].w);
      A[4] = (short)f2bf(xb[kb].x); A[5] = (short)f2bf(xb[kb].y);
      A[6] = (short)f2bf(xb[kb].z); A[7] = (short)f2bf(xb[kb].w);
      accL = __builtin_amdgcn_mfma_f32_16x16x32_bf16(A, BwL[kb], accL, 0, 0, 0);
      accH = __builtin_amdgcn_mfma_f32_16x16x32_bf16(A, BwH[kb], accH, 0, 0, 0);
    }
    // bias + h store (f32) + LDS stash (bf16) for the p/q matmuls
    const float bL = b[n0i], bH = b[16 + n0i];
#pragma unroll
    for (int r = 0; r < 4; ++r) {
      const int row = quad*4 + r;
      const float vL = accL[r] + bL;
      const float vH = accH[r] + bH;
      h[(size_t)(r0 + row)*EMB + n0i]      = vL;
      h[(size_t)(r0 + row)*EMB + 16 + n0i] = vH;
      lds_hb[wv][row*HSTRIDE + n0i]      = f2bf(vL);
      lds_hb[wv][row*HSTRIDE + 16 + n0i] = f2bf(vH);
    }
    // A2 from LDS (wave-private; DS ops wave-ordered, no barrier)
    bf16x8 A2;
#pragma unroll
    for (int j = 0; j < 8; ++j)
      A2[j] = (short)lds_hb[wv][n0i*HSTRIDE + quad*8 + j];
    // B frags for p (w1 rows 0..31) and q (rows 32..63)
    bf16x8 BpL, BpH, BqL, BqH;
#pragma unroll
    for (int j = 0; j < 8; ++j) {
      const int k = quad*8 + j;
      BpL[j] = (short)f2bf(w1[k*EMB + n0i]);
      BpH[j] = (short)f2bf(w1[k*EMB + 16 + n0i]);
      BqL[j] = (short)f2bf(w1[(EMB + k)*EMB + n0i]);
      BqH[j] = (short)f2bf(w1[(EMB + k)*EMB + 16 + n0i]);
    }
    const f32x4 z4 = {0.f,0.f,0.f,0.f};
    f32x4 pL = __builtin_amdgcn_mfma_f32_16x16x32_bf16(A2, BpL, z4, 0, 0, 0);
    f32x4 pH = __builtin_amdgcn_mfma_f32_16x16x32_bf16(A2, BpH, z4, 0, 0, 0);
    f32x4 qL = __builtin_amdgcn_mfma_f32_16x16x32_bf16(A2, BqL, z4, 0, 0, 0);
    f32x4 qH = __builtin_amdgcn_mfma_f32_16x16x32_bf16(A2, BqH, z4, 0, 0, 0);
    // p: fold b1, repack via LDS, 16B stores
    const float b1L = b1[n0i], b1H = b1[16 + n0i];
#pragma unroll
    for (int r = 0; r < 4; ++r) {
      const int row = quad*4 + r;
      lds_pq[wv][row*HSTRIDE + n0i]      = f2bf(pL[r] + b1L);
      lds_pq[wv][row*HSTRIDE + 16 + n0i] = f2bf(pH[r] + b1H);
    }
    {
      const int row2 = lane >> 2;
      const int c8   = (lane & 3)*8;
      const uint4 ov = *(const uint4*)&lds_pq[wv][row2*HSTRIDE + c8];
      *(uint4*)(p + (size_t)(r0 + row2)*EMB + c8) = ov;
    }
    // q: same tile reused (wave-ordered DS)
#pragma unroll
    for (int r = 0; r < 4; ++r) {
      const int row = quad*4 + r;
      lds_pq[wv][row*HSTRIDE + n0i]      = f2bf(qL[r]);
      lds_pq[wv][row*HSTRIDE + 16 + n0i] = f2bf(qH[r]);
    }
    {
      const int row2 = lane >> 2;
      const int c8   = (lane & 3)*8;
      const uint4 ov = *(const uint4*)&lds_pq[wv][row2*HSTRIDE + c8];
      *(uint4*)(q + (size_t)(r0 + row2)*EMB + c8) = ov;
    }
  }
  // fused tail: histogram atomic doubles as rank assignment (one RMW, two uses)
  for (int e = blockIdx.x*256 + threadIdx.x; e < N_EDGES; e += gridDim.x*256) {
    const int d = ei[N_EDGES + e];
    rankp[e] = atomicAdd(&cnt[d], 1);
  }
}

// ---------------- CSR build ----------------
__global__ __launch_bounds__(256) void k_scan_a(const int* __restrict__ cnt,
                                                int* __restrict__ row_ptr, int* __restrict__ bsum) {
  __shared__ int s[256];
  const int gid = blockIdx.x*256 + threadIdx.x;
  const int v = (gid < N_NODES) ? cnt[gid] : 0;
  s[threadIdx.x] = v;
  __syncthreads();
  for (int o = 1; o < 256; o <<= 1) {
    const int t = (threadIdx.x >= o) ? s[threadIdx.x - o] : 0;
    __syncthreads();
    s[threadIdx.x] += t;
    __syncthreads();
  }
  if (gid < N_NODES) row_ptr[gid] = s[threadIdx.x] - v;
  if (threadIdx.x == 255) bsum[blockIdx.x] = s[255];
}

// fused scan_b+c: every block redundantly scans the 196 block sums, adds its offset
__global__ __launch_bounds__(256) void k_scan_bc(int* __restrict__ row_ptr,
                                                 const int* __restrict__ bsum) {
  __shared__ int s[256];
  const int t = threadIdx.x;
  const int v = (t < NODE_GRID) ? bsum[t] : 0;
  s[t] = v;
  __syncthreads();
  for (int o = 1; o < 256; o <<= 1) {
    const int tt = (t >= o) ? s[t - o] : 0;
    __syncthreads();
    s[t] += tt;
    __syncthreads();
  }
  const int off = (blockIdx.x == 0) ? 0 : s[blockIdx.x - 1];
  const int gid = blockIdx.x*256 + t;
  if (gid < N_NODES) row_ptr[gid] += off;
  if (blockIdx.x == 0 && t == 0) row_ptr[N_NODES] = N_EDGES;
}

// fused place + permute: NO atomics — pos = row_ptr[d] + rank[e] (precomputed).
// All reads coalesced; the only cost is the scattered 32B rec store, fully
// pipelined across 800k independent threads. pos clamped defensively: an OOB
// (impossible per construction) becomes a verification failure, not a fault.
__global__ __launch_bounds__(256) void k_place_scatter(
    const int* __restrict__ ei, const float* __restrict__ ea,
    const int* __restrict__ row_ptr, const int* __restrict__ rankp,
    uint4* __restrict__ rec)
{
  const int e = blockIdx.x*256 + threadIdx.x;  // grid 3125 exact
  const int s = ei[e];
  const int d = ei[N_EDGES + e];
  int pos = row_ptr[d] + rankp[e];
  pos = (pos < 0) ? 0 : ((pos >= N_EDGES) ? (N_EDGES - 1) : pos);
  const float4 v0 = ((const float4*)(ea + (size_t)e*ED))[0];
  const float4 v1 = ((const float4*)(ea + (size_t)e*ED))[1];
  const float ev[8] = {v0.x, v0.y, v0.z, v0.w, v1.x, v1.y, v1.z, v1.w};
  unsigned u[4];
#pragma unroll
  for (int j = 0; j < 4; ++j)
    u[j] = (unsigned)f2bf(ev[2*j]) | ((unsigned)f2bf(ev[2*j+1]) << 16);
  uint4* rp = rec + (size_t)pos*2;
  rp[0] = make_uint4((unsigned)s, (unsigned)d, u[0], u[1]);
  rp[1] = make_uint4(u[2], u[3], 0u, 0u);
}

// ---------------- edge kernels (y1 is never materialized in HBM) ----------------
// y1 tile recompute idiom (16 edges):
//   A-frag = ea (bf16, K=8 in quad 0, zero-padded to 32); B = W1b (quad 0 rows).
//   D = mfma(A,B) scattered to f32 LDS tile (stride 33, conflict-free re-read).
//   Reader lane (m=lane&15, quad): row m cols quad*8..+7; p[dst]/q[src] added via
//   coalesced 16B gathers (4 quads = one 64B row). Round to bf16 once.
// k_stats1 and k_msg2 share this exact value path => identical bf16 values.

// k_stats1: ALL rec loads + gathers for the wave's 4 tiles hoisted up front
// (12 independent global loads in flight), then compute.
__global__ __launch_bounds__(256) void k_stats1(
    const unsigned short* __restrict__ pb, const unsigned short* __restrict__ qb,
    const uint4* __restrict__ rec, const float* __restrict__ w1b,
    float* __restrict__ stats)
{
  __shared__ float lds_d[4][16*33];
  __shared__ float lds_s[4][32], lds_q[4][32];
  const int lane = threadIdx.x & 63;
  const int wv   = threadIdx.x >> 6;
  const int l15  = lane & 15;
  const int quad = lane >> 4;

  // B frags for W1b (8x32), K zero-padded: nonzero only in quad 0
  bf16x8 B1lo = {}, B1hi = {};
  if (quad == 0) {
#pragma unroll
    for (int j = 0; j < 8; ++j) {
      B1lo[j] = (short)f2bf(w1b[j*EMB + l15]);
      B1hi[j] = (short)f2bf(w1b[j*EMB + 16 + l15]);
    }
  }

  const int tile0 = blockIdx.x * (4*ST_TPW);
  uint4 RA[ST_TPW], RB[ST_TPW];
#pragma unroll
  for (int t = 0; t < ST_TPW; ++t) {
    const int tile = tile0 + t*4 + wv;           // exact: 0..49999
    const size_t e0 = (size_t)tile * 16;
    const uint4* r4 = rec + (e0 + l15)*2;
    RA[t] = r4[0];
    RB[t] = (quad == 0) ? r4[1] : make_uint4(0u,0u,0u,0u);
  }
  uint4 PG[ST_TPW], QG[ST_TPW];
#pragma unroll
  for (int t = 0; t < ST_TPW; ++t) {
    PG[t] = *(const uint4*)(pb + (size_t)RA[t].y*EMB + quad*8);
    QG[t] = *(const uint4*)(qb + (size_t)RA[t].x*EMB + quad*8);
  }

  float ts[8], tss[8];
#pragma unroll
  for (int j = 0; j < 8; ++j) { ts[j] = 0.f; tss[j] = 0.f; }

#pragma unroll
  for (int t = 0; t < ST_TPW; ++t) {
    bf16x8 A = {};
    if (quad == 0) {
      A[0] = (short)(RA[t].z & 0xFFFFu); A[1] = (short)(RA[t].z >> 16);
      A[2] = (short)(RA[t].w & 0xFFFFu); A[3] = (short)(RA[t].w >> 16);
      A[4] = (short)(RB[t].x & 0xFFFFu); A[5] = (short)(RB[t].x >> 16);
      A[6] = (short)(RB[t].y & 0xFFFFu); A[7] = (short)(RB[t].y >> 16);
    }
    const f32x4 z4 = {0.f,0.f,0.f,0.f};
    f32x4 D0 = __builtin_amdgcn_mfma_f32_16x16x32_bf16(A, B1lo, z4, 0, 0, 0);
    f32x4 D1 = __builtin_amdgcn_mfma_f32_16x16x32_bf16(A, B1hi, z4, 0, 0, 0);
#pragma unroll
    for (int r = 0; r < 4; ++r) {
      const int row = quad*4 + r;
      lds_d[wv][row*33 + l15]      = D0[r];
      lds_d[wv][row*33 + 16 + l15] = D1[r];
    }
    const unsigned pu[4] = {PG[t].x, PG[t].y, PG[t].z, PG[t].w};
    const unsigned qu[4] = {QG[t].x, QG[t].y, QG[t].z, QG[t].w};
#pragma unroll
    for (int jj = 0; jj < 4; ++jj) {
      const float d0 = lds_d[wv][l15*33 + quad*8 + 2*jj];
      const float d1 = lds_d[wv][l15*33 + quad*8 + 2*jj + 1];
      const float v0 = (d0 + bf2f((unsigned short)(pu[jj] & 0xFFFFu)))
                            + bf2f((unsigned short)(qu[jj] & 0xFFFFu));
      const float v1 = (d1 + bf2f((unsigned short)(pu[jj] >> 16)))
                            + bf2f((unsigned short)(qu[jj] >> 16));
      const float w0 = bf2f(f2bf(v0));
      const float w1v = bf2f(f2bf(v1));
      ts[2*jj]   += w0;  tss[2*jj]   = fmaf(w0, w0, tss[2*jj]);
      ts[2*jj+1] += w1v; tss[2*jj+1] = fmaf(w1v, w1v, tss[2*jj+1]);
    }
  }

  // reduce over l15 (lanes in a quad share the same col set quad*8+j)
#pragma unroll
  for (int j = 0; j < 8; ++j) {
    float a = ts[j], b = tss[j];
#pragma unroll
    for (int o = 1; o < 16; o <<= 1) {
      a += __shfl_xor(a, o, 64);
      b += __shfl_xor(b, o, 64);
    }
    ts[j] = a; tss[j] = b;
  }
  if (l15 == 0) {
#pragma unroll
    for (int j = 0; j < 8; ++j) {
      lds_s[wv][quad*8 + j] = ts[j];
      lds_q[wv][quad*8 + j] = tss[j];
    }
  }
  __syncthreads();
  if (threadIdx.x < 64) {
    const int c = threadIdx.x & 31;
    const int kind = threadIdx.x >> 5;
    float v = 0.f;
#pragma unroll
    for (int wq = 0; wq < 4; ++wq)
      v += kind ? lds_q[wq][c] : lds_s[wq][c];
    atomicAdd(stats + ((blockIdx.x & (SREP-1)) << 6) + kind*32 + c, v);
  }
}

// Fused msg1+msg2: recompute y1 per tile, bn1+relu in-register, W2 MFMA,
// write y2 only; stats2. Rotating 1-deep prefetch of next tile's rec + gathers.
__global__ __launch_bounds__(256) void k_msg2(
    const unsigned short* __restrict__ pb, const unsigned short* __restrict__ qb,
    const uint4* __restrict__ rec, const float* __restrict__ w1b,
    const float* __restrict__ stats1, const float* __restrict__ g1, const float* __restrict__ be1,
    const float* __restrict__ w2, const float* __restrict__ b2,
    unsigned short* __restrict__ y, float* __restrict__ stats2)
{
  __shared__ float lds_d[4][16*33];
  __shared__ __align__(16) unsigned short lds_t[4][16*32];
  __shared__ float lds_s[4][32], lds_q[4][32];
  __shared__ float cf[64];

  coef_from_stats(stats1, g1, be1, 1.0f/(float)N_EDGES, cf);

  const int lane = threadIdx.x & 63;
  const int wv   = threadIdx.x >> 6;
  const int l15  = lane & 15;
  const int quad = lane >> 4;

  bf16x8 B1lo = {}, B1hi = {};
  if (quad == 0) {
#pragma unroll
    for (int j = 0; j < 8; ++j) {
      B1lo[j] = (short)f2bf(w1b[j*EMB + l15]);
      B1hi[j] = (short)f2bf(w1b[j*EMB + 16 + l15]);
    }
  }
  bf16x8 Blo, Bhi;   // W2 (32x32)
#pragma unroll
  for (int j = 0; j < 8; ++j) {
    Blo[j] = (short)f2bf(w2[(quad*8 + j)*EMB + l15]);
    Bhi[j] = (short)f2bf(w2[(quad*8 + j)*EMB + 16 + l15]);
  }
  float a1[8], c1[8];
#pragma unroll
  for (int j = 0; j < 8; ++j) {
    a1[j] = cf[quad*8 + j];
    c1[j] = cf[EMB + quad*8 + j];
  }
  const float b2c0 = b2[l15], b2c1 = b2[16 + l15];

  float ts[8], tss[8];
#pragma unroll
  for (int j = 0; j < 8; ++j) { ts[j] = 0.f; tss[j] = 0.f; }

  const int tile0 = blockIdx.x * (4*MSG2_TPW);

  // prologue: tile 0 rec + gathers
  uint4 cRA, cRB, cPG, cQG;
  {
    const size_t e0 = (size_t)(tile0 + wv) * 16;
    const uint4* r4 = rec + (e0 + l15)*2;
    cRA = r4[0];
    cRB = (quad == 0) ? r4[1] : make_uint4(0u,0u,0u,0u);
    cPG = *(const uint4*)(pb + (size_t)cRA.y*EMB + quad*8);
    cQG = *(const uint4*)(qb + (size_t)cRA.x*EMB + quad*8);
  }

#pragma unroll
  for (int t = 0; t < MSG2_TPW; ++t) {
    const size_t e0 = (size_t)(tile0 + t*4 + wv) * 16;

    // issue next tile's rec load before current compute
    uint4 nRA = make_uint4(0u,0u,0u,0u), nRB = make_uint4(0u,0u,0u,0u);
    uint4 nPG = make_uint4(0u,0u,0u,0u), nQG = make_uint4(0u,0u,0u,0u);
    if (t + 1 < MSG2_TPW) {
      const size_t e1 = (size_t)(tile0 + (t+1)*4 + wv) * 16;
      const uint4* r4 = rec + (e1 + l15)*2;
      nRA = r4[0];
      nRB = (quad == 0) ? r4[1] : make_uint4(0u,0u,0u,0u);
    }

    // phase 1: y1 partial via MFMA on ea
    bf16x8 A = {};
    if (quad == 0) {
      A[0] = (short)(cRA.z & 0xFFFFu); A[1] = (short)(cRA.z >> 16);
      A[2] = (short)(cRA.w & 0xFFFFu); A[3] = (short)(cRA.w >> 16);
      A[4] = (short)(cRB.x & 0xFFFFu); A[5] = (short)(cRB.x >> 16);
      A[6] = (short)(cRB.y & 0xFFFFu); A[7] = (short)(cRB.y >> 16);
    }
    const f32x4 z4 = {0.f,0.f,0.f,0.f};
    f32x4 D0 = __builtin_amdgcn_mfma_f32_16x16x32_bf16(A, B1lo, z4, 0, 0, 0);
    f32x4 D1 = __builtin_amdgcn_mfma_f32_16x16x32_bf16(A, B1hi, z4, 0, 0, 0);
#pragma unroll
    for (int r = 0; r < 4; ++r) {
      const int row = quad*4 + r;
      lds_d[wv][row*33 + l15]      = D0[r];
      lds_d[wv][row*33 + 16 + l15] = D1[r];
    }

    // issue next tile's gathers (dep on nRA) mid-body
    if (t + 1 < MSG2_TPW) {
      nPG = *(const uint4*)(pb + (size_t)nRA.y*EMB + quad*8);
      nQG = *(const uint4*)(qb + (size_t)nRA.x*EMB + quad*8);
    }

    // phase 2: combine + bn1 + relu + W2 MFMA + store
    const unsigned pu[4] = {cPG.x, cPG.y, cPG.z, cPG.w};
    const unsigned qu[4] = {cQG.x, cQG.y, cQG.z, cQG.w};
    bf16x8 A2;
#pragma unroll
    for (int jj = 0; jj < 4; ++jj) {
      const float d0 = lds_d[wv][l15*33 + quad*8 + 2*jj];
      const float d1 = lds_d[wv][l15*33 + quad*8 + 2*jj + 1];
      const float v0 = (d0 + bf2f((unsigned short)(pu[jj] & 0xFFFFu)))
                            + bf2f((unsigned short)(qu[jj] & 0xFFFFu));
      const float v1 = (d1 + bf2f((unsigned short)(pu[jj] >> 16)))
                            + bf2f((unsigned short)(qu[jj] >> 16));
      const float w0 = bf2f(f2bf(v0));
      const float w1v = bf2f(f2bf(v1));
      const float r0 = fmaxf(fmaf(a1[2*jj],   w0,  c1[2*jj]),   0.f);
      const float r1 = fmaxf(fmaf(a1[2*jj+1], w1v, c1[2*jj+1]), 0.f);
      A2[2*jj]   = (short)f2bf(r0);
      A2[2*jj+1] = (short)f2bf(r1);
    }

    f32x4 acc0 = {0.f, 0.f, 0.f, 0.f};
    f32x4 acc1 = {0.f, 0.f, 0.f, 0.f};
    acc0 = __builtin_amdgcn_mfma_f32_16x16x32_bf16(A2, Blo, acc0, 0, 0, 0);
    acc1 = __builtin_amdgcn_mfma_f32_16x16x32_bf16(A2, Bhi, acc1, 0, 0, 0);

#pragma unroll
    for (int r = 0; r < 4; ++r) {
      const int row = quad*4 + r;
      lds_t[wv][row*32 + l15]      = f2bf(acc0[r] + b2c0);
      lds_t[wv][row*32 + 16 + l15] = f2bf(acc1[r] + b2c1);
    }
    const uint4 orow = *(const uint4*)&lds_t[wv][(lane>>2)*32 + (lane&3)*8];
    *(uint4*)(y + (e0 + (lane>>2))*EMB + (lane&3)*8) = orow;

    const unsigned uo[4] = {orow.x, orow.y, orow.z, orow.w};
#pragma unroll
    for (int j = 0; j < 4; ++j) {
      const float v0 = bf2f((unsigned short)(uo[j] & 0xFFFFu));
      const float v1 = bf2f((unsigned short)(uo[j] >> 16));
      ts[2*j]   += v0;  tss[2*j]   = fmaf(v0, v0, tss[2*j]);
      ts[2*j+1] += v1;  tss[2*j+1] = fmaf(v1, v1, tss[2*j+1]);
    }

    cRA = nRA; cRB = nRB; cPG = nPG; cQG = nQG;
  }

  // stats2: lane's cols are (lane&3)*8+j -> reduce over lane>>2
#pragma unroll
  for (int j = 0; j < 8; ++j) {
    float s = ts[j], qq = tss[j];
#pragma unroll
    for (int o = 4; o < 64; o <<= 1) {
      s  += __shfl_xor(s, o, 64);
      qq += __shfl_xor(qq, o, 64);
    }
    ts[j] = s; tss[j] = qq;
  }
  if (lane < 4) {
#pragma unroll
    for (int j = 0; j < 8; ++j) {
      lds_s[wv][lane*8 + j] = ts[j];
      lds_q[wv][lane*8 + j] = tss[j];
    }
  }
  __syncthreads();
  if (threadIdx.x < 64) {
    const int c = threadIdx.x & 31;
    const int kind = threadIdx.x >> 5;
    float v = 0.f;
#pragma unroll
    for (int wq = 0; wq < 4; ++wq)
      v += kind ? lds_q[wq][c] : lds_s[wq][c];
    atomicAdd(stats2 + ((blockIdx.x & (SREP-1)) << 6) + kind*32 + c, v);
  }
}

// fused aggr + upd1: aggr lives in LDS only; z1 = concat(h,aggr)@uw1+b; stats.
// Aggregation: lane loads uint4 (8 bf16 cols), 4 lanes/row -> 8 rows/iter in flight.
__global__ __launch_bounds__(256) void k_aggr_upd1(
    const unsigned short* __restrict__ y, const int* __restrict__ row_ptr,
    const float* __restrict__ h,
    const float* __restrict__ stats1, const float* __restrict__ g2, const float* __restrict__ be2,
    const float* __restrict__ uw1, const float* __restrict__ ub1,
    float* __restrict__ z, float* __restrict__ stats2)
{
  __shared__ float cf[64];
  __shared__ float lh[8][32];
  __shared__ float la[8][32];
  __shared__ float rs[4][32], rq[4][32];
  coef_from_stats(stats1, g2, be2, 1.0f/(float)N_EDGES, cf);

  const int g = threadIdx.x >> 5;
  const int l = threadIdx.x & 31;
  const int n = blockIdx.x*8 + g;   // grid 6250 exact -> n < N_NODES always

  // stage h row into LDS (coalesced)
  lh[g][l] = h[(size_t)n*EMB + l];

  // aggregation: 8 rows/iter, lane covers cols c8..c8+7
  const int c8  = (l & 3) * 8;
  const int rof = l >> 2;          // 0..7
  float a[8], b[8];
#pragma unroll
  for (int j = 0; j < 8; ++j) { a[j] = cf[c8 + j]; b[j] = cf[EMB + c8 + j]; }
  const int lo = row_ptr[n], hi = row_ptr[n+1];
  float acc[8];
#pragma unroll
  for (int j = 0; j < 8; ++j) acc[j] = 0.f;
  for (int r = lo + rof; r < hi; r += 8) {
    const uint4 u = *(const uint4*)(y + (size_t)r*EMB + c8);
    const unsigned uu[4] = {u.x, u.y, u.z, u.w};
#pragma unroll
    for (int t = 0; t < 4; ++t) {
      const float v0 = bf2f((unsigned short)(uu[t] & 0xFFFFu));
      const float v1 = bf2f((unsigned short)(uu[t] >> 16));
      acc[2*t]   += fmaxf(fmaf(a[2*t],   v0, b[2*t]),   0.f);
      acc[2*t+1] += fmaxf(fmaf(a[2*t+1], v1, b[2*t+1]), 0.f);
    }
  }
  // reduce over rof (xor 4/8/16 stays within each 32-lane half)
#pragma unroll
  for (int j = 0; j < 8; ++j) {
    float v = acc[j];
    v += __shfl_xor(v, 4, 64);
    v += __shfl_xor(v, 8, 64);
    v += __shfl_xor(v, 16, 64);
    acc[j] = v;
  }
  if (rof == 0) {
#pragma unroll
    for (int j = 0; j < 8; ++j) la[g][c8 + j] = acc[j];
  }
  __syncthreads();

  // upd1: col l of node n
  float accu = ub1[l];
#pragma unroll
  for (int k = 0; k < EMB; ++k) accu = fmaf(lh[g][k], uw1[k*EMB + l], accu);
#pragma unroll
  for (int k = 0; k < EMB; ++k) accu = fmaf(la[g][k], uw1[(EMB + k)*EMB + l], accu);
  z[(size_t)n*EMB + l] = accu;

  // stats
  const float sq = accu*accu;
  const float a2 = accu + __shfl_down(accu, 32, 64);
  const float q2 = sq   + __shfl_down(sq,   32, 64);
  const int wv = threadIdx.x >> 6;
  if ((threadIdx.x & 63) < 32) { rs[wv][l] = a2; rq[wv][l] = q2; }
  __syncthreads();
  if (threadIdx.x < 64) {
    const int c = threadIdx.x & 31;
    const int kind = threadIdx.x >> 5;
    float v = 0.f;
#pragma unroll
    for (int wq = 0; wq < 4; ++wq)
      v += kind ? rq[wq][c] : rs[wq][c];
    atomicAdd(stats2 + ((blockIdx.x & (SREP-1)) << 6) + kind*32 + c, v);
  }
}

// z2 = relu(bn(z1)) @ uw2 + b, in place on z; coef inline; stats. (4-wave col-split)
__global__ __launch_bounds__(256) void k_upd2(
    float* __restrict__ z,
    const float* __restrict__ stats1, const float* __restrict__ g1, const float* __restrict__ be1,
    const float* __restrict__ w, const float* __restrict__ b,
    float* __restrict__ stats2)
{
  __shared__ float cf[64];
  __shared__ float lds_s[32], lds_q[32];
  coef_from_stats(stats1, g1, be1, 1.0f/(float)N_NODES, cf);

  const int lane = threadIdx.x & 63;
  const int wv   = threadIdx.x >> 6;
  const int n  = blockIdx.x*64 + lane;
  const int c0 = wv*8;
  float acc[8];
#pragma unroll
  for (int j = 0; j < 8; ++j) acc[j] = 0.f;
  if (n < N_NODES) {
#pragma unroll
    for (int j = 0; j < 8; ++j) acc[j] = b[c0 + j];
    const float4* zp = (const float4*)(z + (size_t)n*EMB);
#pragma unroll
    for (int k4 = 0; k4 < 8; ++k4) {
      const float4 v = zp[k4];
      const float mv[4] = {v.x, v.y, v.z, v.w};
#pragma unroll
      for (int t = 0; t < 4; ++t) {
        const int k = 4*k4 + t;
        const float m = fmaxf(fmaf(cf[k], mv[t], cf[EMB + k]), 0.f);
        const float* wk = w + k*EMB + c0;
#pragma unroll
        for (int j = 0; j < 8; ++j) acc[j] = fmaf(m, wk[j], acc[j]);
      }
    }
  }
  float ts[8], tss[8];
#pragma unroll
  for (int j = 0; j < 8; ++j) { ts[j] = acc[j]; tss[j] = acc[j]*acc[j]; }
  wave_stats_atomic(ts, tss, lds_s, lds_q, stats2);  // barrier inside
  if (n < N_NODES) {
    float4 o0, o1;
    o0.x = acc[0]; o0.y = acc[1]; o0.z = acc[2]; o0.w = acc[3];
    o1.x = acc[4]; o1.y = acc[5]; o1.z = acc[6]; o1.w = acc[7];
    *(float4*)(z + (size_t)n*EMB + c0)     = o0;
    *(float4*)(z + (size_t)n*EMB + c0 + 4) = o1;
  }
}

// h += relu(bn(z2)); p/q (bf16, b1_next folded into p) via LDS hn-exchange.
__global__ __launch_bounds__(256) void k_resid_pq(
    float* __restrict__ h, const float* __restrict__ z,
    const float* __restrict__ stats, const float* __restrict__ g, const float* __restrict__ be,
    const float* __restrict__ w1_next, const float* __restrict__ b1_next,
    unsigned short* __restrict__ p, unsigned short* __restrict__ q)
{
  __shared__ float cf[64];
  __shared__ float lds_h[64][33];
  coef_from_stats(stats, g, be, 1.0f/(float)N_NODES, cf);

  const int lane = threadIdx.x & 63;
  const int wv   = threadIdx.x >> 6;
  const int n  = blockIdx.x*64 + lane;
  const int c0 = wv*8;
  if (n < N_NODES) {
    const float4* zp = (const float4*)(z + (size_t)n*EMB + c0);
    float4* hp = (float4*)(h + (size_t)n*EMB + c0);
    float hn[8];
    const float4 z0 = zp[0], z1 = zp[1];
    const float4 h0 = hp[0], h1 = hp[1];
    const float zv[8] = {z0.x, z0.y, z0.z, z0.w, z1.x, z1.y, z1.z, z1.w};
    const float hv[8] = {h0.x, h0.y, h0.z, h0.w, h1.x, h1.y, h1.z, h1.w};
#pragma unroll
    for (int j = 0; j < 8; ++j) {
      const int k = c0 + j;
      hn[j] = hv[j] + fmaxf(fmaf(cf[k], zv[j], cf[EMB + k]), 0.f);
      lds_h[lane][k] = hn[j];
    }
    float4 o0, o1;
    o0.x = hn[0]; o0.y = hn[1]; o0.z = hn[2]; o0.w = hn[3];
    o1.x = hn[4]; o1.y = hn[5]; o1.z = hn[6]; o1.w = hn[7];
    hp[0] = o0; hp[1] = o1;
  }
  __syncthreads();
  if (n < N_NODES && w1_next) {
    float ap[8], aq[8];
#pragma unroll
    for (int j = 0; j < 8; ++j) { ap[j] = b1_next[c0 + j]; aq[j] = 0.f; }
#pragma unroll
    for (int k = 0; k < EMB; ++k) {
      const float hvv = lds_h[lane][k];
      const float* wp = w1_next + k*EMB + c0;
      const float* wq = w1_next + (EMB + k)*EMB + c0;
#pragma unroll
      for (int j = 0; j < 8; ++j) ap[j] = fmaf(hvv, wp[j], ap[j]);
#pragma unroll
      for (int j = 0; j < 8; ++j) aq[j] = fmaf(hvv, wq[j], aq[j]);
    }
    unsigned up[4], uq[4];
#pragma unroll
    for (int j = 0; j < 4; ++j) {
      up[j] = (unsigned)f2bf(ap[2*j]) | ((unsigned)f2bf(ap[2*j+1]) << 16);
      uq[j] = (unsigned)f2bf(aq[2*j]) | ((unsigned)f2bf(aq[2*j+1]) << 16);
    }
    uint4 op; op.x = up[0]; op.y = up[1]; op.z = up[2]; op.w = up[3];
    uint4 oq; oq.x = uq[0]; oq.y = uq[1]; oq.z = uq[2]; oq.w = uq[3];
    *(uint4*)(p + (size_t)n*EMB + c0) = op;
    *(uint4*)(q + (size_t)n*EMB + c0) = oq;
  }
}

// per-graph mean pool + final linear
__global__ void k_pool(const float* __restrict__ h, const int* __restrict__ batch,
                       const float* __restrict__ pw, const float* __restrict__ pb,
                       float* __restrict__ out)
{
  __shared__ float sred[256];
  __shared__ float hg[EMB];
  const int b = blockIdx.x;
  int lo = 0, hi = N_NODES;
  while (lo < hi) { int m = (lo + hi) >> 1; if (batch[m] < b) lo = m + 1; else hi = m; }
  const int start = lo;
  hi = N_NODES;
  while (lo < hi) { int m = (lo + hi) >> 1; if (batch[m] < b + 1) lo = m + 1; else hi = m; }
  const int end = lo;

  const int c = threadIdx.x & (EMB-1);
  const int r = threadIdx.x >> 5;
  float s = 0.f;
  for (int n = start + r; n < end; n += 8) s += h[(size_t)n*EMB + c];
  sred[threadIdx.x] = s;
  __syncthreads();
  if (threadIdx.x < EMB) {
    float tot = 0.f;
#pragma unroll
    for (int r2 = 0; r2 < 8; ++r2) tot += sred[r2*EMB + threadIdx.x];
    const float cnt = (float)(end - start);
    hg[threadIdx.x] = tot / fmaxf(cnt, 1.f);
  }
  __syncthreads();
  if (threadIdx.x < OUTD) {
    float acc = pb[threadIdx.x];
#pragma unroll
    for (int cc = 0; cc < EMB; ++cc) acc = fmaf(hg[cc], pw[cc*OUTD + threadIdx.x], acc);
    out[b*OUTD + threadIdx.x] = acc;
  }
}

// ---------------- host ----------------

extern "C" void kernel_launch(void* const* d_in, const int* in_sizes, int n_in,
                              void* d_out, int out_size, void* d_ws, size_t ws_size,
                              hipStream_t stream) {
  const float* x        = (const float*)d_in[0];
  const int*   ei       = (const int*)  d_in[1];
  const float* ea       = (const float*)d_in[2];
  const int*   batch    = (const int*)  d_in[3];
  const float* lin_in_w = (const float*)d_in[4];
  const float* lin_in_b = (const float*)d_in[5];
  const float* msg_w1   = (const float*)d_in[6];
  const float* msg_b1   = (const float*)d_in[7];
  const float* msg_g1   = (const float*)d_in[8];
  const float* msg_be1  = (const float*)d_in[9];
  const float* msg_w2   = (const float*)d_in[10];
  const float* msg_b2   = (const float*)d_in[11];
  const float* msg_g2   = (const float*)d_in[12];
  const float* msg_be2  = (const float*)d_in[13];
  const float* upd_w1   = (const float*)d_in[14];
  const float* upd_b1   = (const float*)d_in[15];
  const float* upd_g1   = (const float*)d_in[16];
  const float* upd_be1  = (const float*)d_in[17];
  const float* upd_w2   = (const float*)d_in[18];
  const float* upd_b2   = (const float*)d_in[19];
  const float* upd_g2   = (const float*)d_in[20];
  const float* upd_be2  = (const float*)d_in[21];
  const float* pred_w   = (const float*)d_in[22];
  const float* pred_b   = (const float*)d_in[23];
  float* out = (float*)d_out;

  // Workspace layout (~100 MB)
  char* wsb = (char*)d_ws;
  unsigned short* y  = (unsigned short*)wsb;                            // E*32 bf16 (y2, CSR order)
  uint4* rec = (uint4*)(wsb + (size_t)N_EDGES*EMB*2);                   // E x 32B records (CSR order)
  unsigned short* p  = (unsigned short*)(rec + (size_t)N_EDGES*2);      // N*32 bf16
  unsigned short* q  = p + (size_t)N_NODES*EMB;                         // N*32 bf16
  float* h       = (float*)(q + (size_t)N_NODES*EMB);                   // N*32 f32
  float* z       = h + (size_t)N_NODES*EMB;                             // N*32 f32 (z1/z2 in place)
  float* stats   = z + (size_t)N_NODES*EMB;                             // 16 x SREP x 64
  int*   cnt     = (int*)(stats + 16*SREP*64);                          // N (hist; atomic also yields rank)
  int*   row_ptr = cnt + N_NODES;
  int*   bsum    = row_ptr + N_NODES + 1;
  int*   rankp   = bsum + 256;                                          // E x 4B within-node rank
  const size_t need = ((size_t)((char*)(rankp + N_EDGES) - wsb));
  if (ws_size < need) return;

  hipMemsetAsync(stats, 0, (16*SREP*64 + N_NODES)*sizeof(float), stream);

  k_lin_in_pq<<<LIN_GRID, 256, 0, stream>>>(x, lin_in_w, lin_in_b, msg_w1, msg_b1, ei,
                                            h, p, q, cnt, rankp);
  k_scan_a<<<NODE_GRID, 256, 0, stream>>>(cnt, row_ptr, bsum);
  k_scan_bc<<<NODE_GRID, 256, 0, stream>>>(row_ptr, bsum);
  k_place_scatter<<<EDGE_GRID, 256, 0, stream>>>(ei, ea, row_ptr, rankp, rec);

  for (int l = 0; l < NLAYERS; ++l) {
    const int st = l*4;
    const float* w1  = msg_w1 + (size_t)l*(2*EMB+ED)*EMB;
    const float* w1b = w1 + (size_t)2*EMB*EMB;
    const float* w2  = msg_w2 + (size_t)l*EMB*EMB;
    const float* uw1 = upd_w1 + (size_t)l*(2*EMB)*EMB;
    const float* uw2 = upd_w2 + (size_t)l*EMB*EMB;
    const float* w1_next = (l+1 < NLAYERS) ? msg_w1 + (size_t)(l+1)*(2*EMB+ED)*EMB : nullptr;
    const float* b1_next = (l+1 < NLAYERS) ? msg_b1 + (size_t)(l+1)*EMB : nullptr;

    k_stats1<<<ST_GRID, 256, 0, stream>>>(p, q, rec, w1b, stats + (size_t)st*SREP*64);
    k_msg2<<<MSG2_GRID, 256, 0, stream>>>(p, q, rec, w1b,
                                          stats + (size_t)st*SREP*64,
                                          msg_g1 + l*EMB, msg_be1 + l*EMB,
                                          w2, msg_b2 + l*EMB,
                                          y, stats + (size_t)(st+1)*SREP*64);
    k_aggr_upd1<<<AU_GRID, 256, 0, stream>>>(y, row_ptr, h,
                                             stats + (size_t)(st+1)*SREP*64,
                                             msg_g2 + l*EMB, msg_be2 + l*EMB,
                                             uw1, upd_b1 + l*EMB,
                                             z, stats + (size_t)(st+2)*SREP*64);
    k_upd2<<<NODE4_GRID, 256, 0, stream>>>(z, stats + (size_t)(st+2)*SREP*64,
                                           upd_g1 + l*EMB, upd_be1 + l*EMB,
                                           uw2, upd_b2 + l*EMB, stats + (size_t)(st+3)*SREP*64);
    k_resid_pq<<<NODE4_GRID, 256, 0, stream>>>(h, z, stats + (size_t)(st+3)*SREP*64,
                                               upd_g2 + l*EMB, upd_be2 + l*EMB,
                                               w1_next, b1_next, p, q);
  }

  k_pool<<<NB, 256, 0, stream>>>(h, batch, pred_w, pred_b, out);
}